// Round 16
// baseline (175.230 us; speedup 1.0000x reference)
//
#include <hip/hip_runtime.h>
#include <math.h>

// NetVLAD fp32: N=32, D=512, K=64, P=1024
// R15 lesson (completes the allocator model): VGPR cap = 512 / (waves/SIMD
// implied by LDS-permitted blocks/CU). k2a's 32KB LDS -> 4 blk/CU -> cap 64
// -> load-ILP starvation (VALU 15%). Fix: LDS>=64KB forces 2 blk/CU -> cap
// 128. Pipe-split thesis unchanged: A-side on VMEM (L2), x-side on DS.
// k0 : wt[d][k] transpose.
// k1a: R13-PROVEN LDS-staged GEMM body (~36us) + R15 epilogue:
//      softmax -> A''[n][pc][q][k][jp] quad-major + spart[n][16][k].
// k2a: A from GLOBAL (batched af[8], 1KB line-dense per instr group,
//      L2-resident) + x in LDS (XOR-quad swizzle, conflict-free b128).
//      LDS padded to 72KB (VGPR cap 128). acc[8][4], 512 thr, (512,2).
// k2c: intra + global L2 norm in place (proven, 16 d-tiles).

namespace {

constexpr int NI   = 32;
constexpr int DIMC = 512;
constexpr int KCL  = 64;
constexpr int PIXN = 1024;
constexpr float EPSF = 1e-12f;

#define AS1 __attribute__((address_space(1)))
#define AS3 __attribute__((address_space(3)))

__device__ __forceinline__ void glds16(const float* g, float* l) {
  __builtin_amdgcn_global_load_lds((const AS1 void*)g, (AS3 void*)l, 16, 0, 0);
}

// ---------------------------------------------------------------------------
__global__ __launch_bounds__(256) void k0_wt(const float* __restrict__ w,
                                             float* __restrict__ wt) {
  const int i = blockIdx.x * 256 + threadIdx.x;   // 32768, wt[d][k]
  wt[i] = w[(size_t)(i & 63) * DIMC + (i >> 6)];
}

// ---------------------------------------------------------------------------
// k1a: 512 blocks = (n, pg 0..15 [64p]); 512 thr = 8 waves, (512,2).
// R13-proven LDS-staged body; wave w owns dd in [8w,8w+8) per 64d chunk.
// Lane (lk,ld): k=8lk+i, p=pb+8ld+j. Epilogue: softmax -> A'' + spart.
// ---------------------------------------------------------------------------
__global__ __launch_bounds__(512, 2) void k1a_logits(
    const float* __restrict__ x, const float* __restrict__ wt,
    const float* __restrict__ conv_b, float* __restrict__ Ad,
    float* __restrict__ spart)
{
  __shared__ float smem[16384];       // xs[2][4096] | wl[2][4096]; scr=smem
  float* const xs0 = smem;            // [buf][dd*64 + p]
  float* const wl0 = smem + 8192;     // [buf][dd*64 + k]
  float* const scr = smem;            // 4 slots x 4096 (staging dead)

  const int tid = threadIdx.x;
  const int w  = __builtin_amdgcn_readfirstlane(tid >> 6);   // 0..7
  const int l  = tid & 63;
  const int lk = l & 7, ld = l >> 3;
  const int bid = blockIdx.x;
  const int xcd = bid & 7, rest = bid >> 3;   // n -> XCD n%8
  const int n  = xcd + ((rest & 3) << 3);
  const int pg = rest >> 2;                   // 0..15
  const int pb = pg << 6;

  const float* xn = x + (size_t)n * DIMC * PIXN + pb;
  const int i0 = tid, i1 = tid + 512;

  glds16(xn + (size_t)(i0 >> 4) * PIXN + ((i0 & 15) << 2), xs0 + (i0 << 2));
  glds16(xn + (size_t)(i1 >> 4) * PIXN + ((i1 & 15) << 2), xs0 + (i1 << 2));
  glds16(wt + (i0 << 2), wl0 + (i0 << 2));
  glds16(wt + (i1 << 2), wl0 + (i1 << 2));

  float acc[8][8];
#pragma unroll
  for (int i = 0; i < 8; ++i)
#pragma unroll
    for (int j = 0; j < 8; ++j) acc[i][j] = 0.0f;

  for (int ch = 0; ch < 8; ++ch) {    // 512 d in chunks of 64
    const int cur = ch & 1;
    __syncthreads();                  // chunk ch landed
    if (ch < 7) {
      const float* xc = xn + (size_t)((ch + 1) * 64) * PIXN;
      const float* wc = wt + (ch + 1) * 4096;
      glds16(xc + (size_t)(i0 >> 4) * PIXN + ((i0 & 15) << 2),
             xs0 + (cur ^ 1) * 4096 + (i0 << 2));
      glds16(xc + (size_t)(i1 >> 4) * PIXN + ((i1 & 15) << 2),
             xs0 + (cur ^ 1) * 4096 + (i1 << 2));
      glds16(wc + (i0 << 2), wl0 + (cur ^ 1) * 4096 + (i0 << 2));
      glds16(wc + (i1 << 2), wl0 + (cur ^ 1) * 4096 + (i1 << 2));
    }
    const float* wr = wl0 + cur * 4096 + (w << 9) + (lk << 3);
    const float* xr = xs0 + cur * 4096 + (w << 9) + (ld << 3);
#pragma unroll
    for (int dd = 0; dd < 8; ++dd) {
      const float4 wa = *reinterpret_cast<const float4*>(wr + (dd << 6));
      const float4 wb = *reinterpret_cast<const float4*>(wr + (dd << 6) + 4);
      const float4 xa = *reinterpret_cast<const float4*>(xr + (dd << 6));
      const float4 xb = *reinterpret_cast<const float4*>(xr + (dd << 6) + 4);
      const float wv[8] = {wa.x, wa.y, wa.z, wa.w, wb.x, wb.y, wb.z, wb.w};
      const float xv[8] = {xa.x, xa.y, xa.z, xa.w, xb.x, xb.y, xb.z, xb.w};
#pragma unroll
      for (int i = 0; i < 8; ++i)
#pragma unroll
        for (int j = 0; j < 8; ++j)
          acc[i][j] = fmaf(wv[i], xv[j], acc[i][j]);
    }
  }
  __syncthreads();                    // staging dead

#define TST(RB)                                                              \
  do {                                                                       \
    _Pragma("unroll") for (int i = 0; i < 8; ++i) {                          \
      *reinterpret_cast<float4*>((RB) + ((2 * i) << 8) + (l << 2)) =         \
          make_float4(acc[i][0], acc[i][1], acc[i][2], acc[i][3]);           \
      *reinterpret_cast<float4*>((RB) + ((2 * i + 1) << 8) + (l << 2)) =     \
          make_float4(acc[i][4], acc[i][5], acc[i][6], acc[i][7]);           \
    }                                                                        \
  } while (0)
#define TADD(RB)                                                             \
  do {                                                                       \
    _Pragma("unroll") for (int i = 0; i < 8; ++i) {                          \
      const float4 t0 = *reinterpret_cast<const float4*>(                    \
          (RB) + ((2 * i) << 8) + (l << 2));                                 \
      const float4 t1 = *reinterpret_cast<const float4*>(                    \
          (RB) + ((2 * i + 1) << 8) + (l << 2));                             \
      acc[i][0] += t0.x; acc[i][1] += t0.y; acc[i][2] += t0.z;               \
      acc[i][3] += t0.w; acc[i][4] += t1.x; acc[i][5] += t1.y;               \
      acc[i][6] += t1.z; acc[i][7] += t1.w;                                  \
    }                                                                        \
  } while (0)

  if (w == 4) TST(scr);
  if (w == 5) TST(scr + 4096);
  if (w == 6) TST(scr + 8192);
  if (w == 7) TST(scr + 12288);
  __syncthreads();
  if (w < 4) TADD(scr + w * 4096);
  __syncthreads();
  if (w == 2) TST(scr);
  if (w == 3) TST(scr + 4096);
  __syncthreads();
  if (w < 2) TADD(scr + w * 4096);
  __syncthreads();
  if (w == 1) TST(scr);
  __syncthreads();

  if (w == 0) {
    TADD(scr);                        // full logits, fixed tree order
    const float4 b0 = *reinterpret_cast<const float4*>(conv_b + (lk << 3));
    const float4 b1 = *reinterpret_cast<const float4*>(conv_b + (lk << 3) + 4);
    const float bv[8] = {b0.x, b0.y, b0.z, b0.w, b1.x, b1.y, b1.z, b1.w};
#pragma unroll
    for (int i = 0; i < 8; ++i)
#pragma unroll
      for (int j = 0; j < 8; ++j) acc[i][j] += bv[i];
    float m[8], S[8];
#pragma unroll
    for (int j = 0; j < 8; ++j) {
      m[j] = acc[0][j];
#pragma unroll
      for (int i = 1; i < 8; ++i) m[j] = fmaxf(m[j], acc[i][j]);
      m[j] = fmaxf(m[j], __shfl_xor(m[j], 1, 64));
      m[j] = fmaxf(m[j], __shfl_xor(m[j], 2, 64));
      m[j] = fmaxf(m[j], __shfl_xor(m[j], 4, 64));
      S[j] = 0.0f;
#pragma unroll
      for (int i = 0; i < 8; ++i) {
        acc[i][j] = __expf(acc[i][j] - m[j]);
        S[j] += acc[i][j];
      }
      S[j] += __shfl_xor(S[j], 1, 64);
      S[j] += __shfl_xor(S[j], 2, 64);
      S[j] += __shfl_xor(S[j], 4, 64);
      S[j] = 1.0f / S[j];
    }
    // A''[n][pg][q][k][jp] quad-major (R15-proven): q = p-quad in chunk,
    // jp = p&3. Lane writes quads 2ld (acc[i][0..3]) and 2ld+1 (acc[i][4..7]).
    float* abase = Ad + (((size_t)n * 16 + pg) * 16 + (ld << 1)) * 256 + (lk << 3) * 4;
#pragma unroll
    for (int i = 0; i < 8; ++i) {
      *reinterpret_cast<float4*>(abase + i * 4) =
          make_float4(acc[i][0] * S[0], acc[i][1] * S[1],
                      acc[i][2] * S[2], acc[i][3] * S[3]);
      *reinterpret_cast<float4*>(abase + 256 + i * 4) =
          make_float4(acc[i][4] * S[4], acc[i][5] * S[5],
                      acc[i][6] * S[6], acc[i][7] * S[7]);
    }
    // spart[n][pg][k]: column sums over this block's 64 p (fixed order)
#pragma unroll
    for (int i = 0; i < 8; ++i) {
      float sp = acc[i][0] * S[0] + acc[i][1] * S[1] + acc[i][2] * S[2] +
                 acc[i][3] * S[3] + acc[i][4] * S[4] + acc[i][5] * S[5] +
                 acc[i][6] * S[6] + acc[i][7] * S[7];
      sp += __shfl_xor(sp, 8, 64);
      sp += __shfl_xor(sp, 16, 64);
      sp += __shfl_xor(sp, 32, 64);
      if (ld == 0) spart[((size_t)n * 16 + pg) * KCL + (lk << 3) + i] = sp;
    }
  }
#undef TST
#undef TADD
}

// ---------------------------------------------------------------------------
// k2a: 512 blocks = (n, dt 0..15 [32d]); 512 thr = 8 waves, (512,2).
// LDS 72KB (xL 2x2048 U scr 4x2048 + pad) -> 2 blk/CU -> VGPR cap 128.
// Lane (lk,ld): k=8lk+ii, d=32dt+4ld+jd. Wave w: p-quads {2w,2w+1}/chunk.
// A from GLOBAL A'' batched af[8] (1KB contiguous per lane-group, L2);
// x chunk [32][64] in LDS via glds16, XOR-quad swizzle -> conflict-free.
// ---------------------------------------------------------------------------
__global__ __launch_bounds__(512, 2) void k2a_vlad(
    const float* __restrict__ x, const float* __restrict__ Ad,
    const float* __restrict__ spart, const float* __restrict__ cent,
    float* __restrict__ out, float* __restrict__ ssqp)
{
  __shared__ float smem[18432];   // 72KB: xL[2][2048] U scr 4x2048; pad->cap128
  float* const xL0 = smem;
  float* const scr = smem;

  const int tid = threadIdx.x;
  const int w  = __builtin_amdgcn_readfirstlane(tid >> 6);   // 0..7
  const int l  = tid & 63;
  const int lk = l & 7, ld = l >> 3;
  const int bid = blockIdx.x;
  const int xcd = bid & 7, rest = bid >> 3;
  const int n  = xcd + ((rest & 3) << 3);
  const int dt = rest >> 2;           // 0..15
  const int d0 = dt << 5;             // 32-d tile

  const float* an = Ad + (size_t)n * 16 * 16 * 256;          // A''[n]
  const float* xn = x + ((size_t)n * DIMC + d0) * PIXN;
  // x staging: thread i -> LDS float-offset 4i (linear); row=i>>4, qs=i&15;
  // source logical quad = qs ^ ((row>>2)&7)
  const int srow = tid >> 4, sqs = tid & 15;
  const int sq  = (sqs ^ ((srow >> 2) & 7));
  const float* xsrc = xn + (size_t)srow * PIXN + (sq << 2);

  // prologue: chunk 0
  glds16(xsrc, xL0 + (tid << 2));

  float acc[8][4];
#pragma unroll
  for (int ii = 0; ii < 8; ++ii)
#pragma unroll
    for (int jd = 0; jd < 4; ++jd) acc[ii][jd] = 0.0f;
  __syncthreads();

  for (int ch = 0; ch < 16; ++ch) {   // P in chunks of 64
    const int cur = ch & 1;
    const float* xLc = xL0 + cur * 2048;
    if (ch < 15)
      glds16(xsrc + (ch + 1) * 64, xL0 + (cur ^ 1) * 2048 + (tid << 2));
    const float* ac = an + (size_t)ch * 16 * 256;   // chunk's 16 quads x 256
#pragma unroll
    for (int q = 0; q < 2; ++q) {
      const int pq = (w << 1) + q;
      // batch-issue: 8 independent global A-quads (128B contiguous/lane)
      const float* aq = ac + (size_t)pq * 256 + (lk << 3) * 4;
      float4 af[8];
#pragma unroll
      for (int ii = 0; ii < 8; ++ii)
        af[ii] = *reinterpret_cast<const float4*>(aq + ii * 4);
      float4 xf[4];
#pragma unroll
      for (int jd = 0; jd < 4; ++jd)
        xf[jd] = *reinterpret_cast<const float4*>(
            xLc + ((ld << 2) + jd) * 64 + ((pq ^ ld) << 2));
#pragma unroll
      for (int ii = 0; ii < 8; ++ii) {
#pragma unroll
        for (int jd = 0; jd < 4; ++jd) {
          acc[ii][jd] = fmaf(af[ii].x, xf[jd].x, acc[ii][jd]);
          acc[ii][jd] = fmaf(af[ii].y, xf[jd].y, acc[ii][jd]);
          acc[ii][jd] = fmaf(af[ii].z, xf[jd].z, acc[ii][jd]);
          acc[ii][jd] = fmaf(af[ii].w, xf[jd].w, acc[ii][jd]);
        }
      }
    }
    __syncthreads();
  }

  // 3-round lane-keyed tree: 8 quads/lane, slot stride 2048 floats
#define TST2(RB)                                                             \
  do {                                                                       \
    _Pragma("unroll") for (int ii = 0; ii < 8; ++ii)                         \
      *reinterpret_cast<float4*>((RB) + (ii << 8) + (l << 2)) =              \
          make_float4(acc[ii][0], acc[ii][1], acc[ii][2], acc[ii][3]);       \
  } while (0)
#define TADD2(RB)                                                            \
  do {                                                                       \
    _Pragma("unroll") for (int ii = 0; ii < 8; ++ii) {                       \
      const float4 t0 = *reinterpret_cast<const float4*>(                    \
          (RB) + (ii << 8) + (l << 2));                                      \
      acc[ii][0] += t0.x; acc[ii][1] += t0.y;                                \
      acc[ii][2] += t0.z; acc[ii][3] += t0.w;                                \
    }                                                                        \
  } while (0)

  if (w >= 4) TST2(scr + (w - 4) * 2048);
  __syncthreads();
  if (w < 4) TADD2(scr + w * 2048);
  __syncthreads();
  if (w == 2) TST2(scr);
  if (w == 3) TST2(scr + 2048);
  __syncthreads();
  if (w < 2) TADD2(scr + w * 2048);
  __syncthreads();
  if (w == 1) TST2(scr);
  __syncthreads();

  if (w == 0) {
    TADD2(scr);   // final, deterministic fixed tree
#pragma unroll
    for (int ii = 0; ii < 8; ++ii) {
      const int k = (lk << 3) + ii;
      float s = 0.0f;
#pragma unroll
      for (int pt = 0; pt < 16; ++pt)                  // fixed order
        s += spart[((size_t)n * 16 + pt) * KCL + k];
      const float4 cf = *reinterpret_cast<const float4*>(
          cent + (size_t)k * DIMC + d0 + (ld << 2));
      float r[4];
      r[0] = acc[ii][0] - s * cf.x;
      r[1] = acc[ii][1] - s * cf.y;
      r[2] = acc[ii][2] - s * cf.z;
      r[3] = acc[ii][3] - s * cf.w;
      *reinterpret_cast<float4*>(
          out + ((size_t)n * KCL + k) * DIMC + d0 + (ld << 2)) =
          make_float4(r[0], r[1], r[2], r[3]);
      float q = fmaf(r[0], r[0], fmaf(r[1], r[1], fmaf(r[2], r[2], r[3] * r[3])));
      q += __shfl_xor(q, 8, 64);
      q += __shfl_xor(q, 16, 64);
      q += __shfl_xor(q, 32, 64);
      if (ld == 0) ssqp[((size_t)n * KCL + k) * 16 + dt] = q;
    }
  }
#undef TST2
#undef TADD2
}

// ---------------------------------------------------------------------------
// k2c: 256 blocks = (n, kc 0..7); intra + global norm in place (proven,
// ssqp has 16 d-tiles per (n,k)).
// ---------------------------------------------------------------------------
__global__ __launch_bounds__(256) void k2c_norm(
    const float* __restrict__ ssqp, float* __restrict__ out)
{
  __shared__ float invs[64];
  __shared__ float gsh;
  const int tid = threadIdx.x;
  const int n  = blockIdx.x >> 3;
  const int kc = blockIdx.x & 7;
  if (tid < 64) {
    float ssq = 0.0f;
#pragma unroll
    for (int dt = 0; dt < 16; ++dt)
      ssq += ssqp[((size_t)n * KCL + tid) * 16 + dt];   // fixed order
    const float inv = 1.0f / fmaxf(sqrtf(ssq), EPSF);
    invs[tid] = inv;
    float rqv = ssq * inv * inv;
#pragma unroll
    for (int off = 32; off > 0; off >>= 1) rqv += __shfl_xor(rqv, off, 64);
    if (tid == 0) gsh = 1.0f / fmaxf(sqrtf(rqv), EPSF);
  }
  __syncthreads();
  const float sc = invs[(kc << 3) + (tid >> 5)] * gsh;
  float* o = out + ((size_t)n * KCL + (kc << 3)) * DIMC + tid * 16;
#pragma unroll
  for (int q = 0; q < 4; ++q) {
    float4 v = *reinterpret_cast<float4*>(o + (q << 2));
    v.x *= sc; v.y *= sc; v.z *= sc; v.w *= sc;
    *reinterpret_cast<float4*>(o + (q << 2)) = v;
  }
}

}  // namespace

extern "C" void kernel_launch(void* const* d_in, const int* in_sizes, int n_in,
                              void* d_out, int out_size, void* d_ws, size_t ws_size,
                              hipStream_t stream) {
  (void)in_sizes; (void)n_in; (void)out_size; (void)ws_size;
  const float* x      = (const float*)d_in[0];
  const float* cent   = (const float*)d_in[1];
  const float* conv_w = (const float*)d_in[2];
  const float* conv_b = (const float*)d_in[3];
  float* out = (float*)d_out;
  float* ws  = (float*)d_ws;

  // ws (floats): A'' 2097152 | wt 32768 | spart 32768 | ssqp 32768 = 8.65 MB
  float* Ad    = ws;
  float* wt    = Ad + (size_t)NI * PIXN * KCL;
  float* spart = wt + 32768;
  float* ssqp  = spart + 32768;

  k0_wt     <<<128, 256, 0, stream>>>(conv_w, wt);
  k1a_logits<<<512, 512, 0, stream>>>(x, wt, conv_b, Ad, spart);
  k2a_vlad  <<<512, 512, 0, stream>>>(x, Ad, spart, cent, out, ssqp);
  k2c_norm  <<<256, 256, 0, stream>>>(ssqp, out);
}